// Round 10
// baseline (340.804 us; speedup 1.0000x reference)
//
#include <hip/hip_runtime.h>
#include <math.h>

#define IN_F 67
#define F1   80   // H1*C1
#define NH1  10
#define NC1  8

#define GN   64           // nodes per GEMM block
#define KS   104          // sWt row stride in h16 (208 B, 16B-aligned frags)
#define PKS  96           // packed row stride in h16 (192 B = 2 x 96 B half-rows)
#define CAP  64           // bucket capacity per node (P(deg>63) ~ 1e-17)
#define CPAD 16           // cursor stride in ints (64 B: 1 atomic counter/line)
#define NFILL 1024        // bucket-fill blocks at the front of the k_front grid

typedef _Float16 h16;
typedef h16 h16x2 __attribute__((ext_vector_type(2)));
typedef h16 h16x8 __attribute__((ext_vector_type(8)));
typedef float f32x4 __attribute__((ext_vector_type(4)));
typedef float f32x4u __attribute__((ext_vector_type(4), aligned(4)));

// ---------------- front: block-specialized bucket fill | MFMA GEMM --------
// blocks [0,NFILL): single-pass bucket CSR build, int4-vectorized edge loads,
//   4 independent atomic+scatter chains per iteration (MLP), padded counters.
// blocks [NFILL, NFILL+nbG): lean MFMA GEMM + logits. pk half-row layout per
//   head-group g (bytes g*96 .. g*96+95): 5 heads x 8ch fp16 (80 B), a_src
//   for those 5 heads fp16 (10 B), 6 B pad -> agg reads 6 contiguous 16B.
__global__ __launch_bounds__(256)
void k_front(const float* __restrict__ x, const float* __restrict__ W,
             const float* __restrict__ att_s, const float* __restrict__ att_d,
             const int* __restrict__ ei, int* __restrict__ cursor,
             int* __restrict__ csr, h16* __restrict__ pk,
             float* __restrict__ a_dst, int N, int E, int EN) {
    __shared__ __align__(16) char smem[GN * 81 * 4];   // 20736 B
    h16*   sWt = (h16*)smem;                           // 80*KS*2 = 16640 B
    float* sO  = (float*)smem;                         // aliased after barrier

    const int tid = threadIdx.x;

    if ((int)blockIdx.x < NFILL) {
        // ---- bucket-fill blocks: real edges, 4-wide vectorized ----
        const int E4 = E & ~3;
        int e0 = (blockIdx.x * 256 + tid) * 4;
        int stride4 = NFILL * 256 * 4;
        for (int e = e0; e < E4; e += stride4) {
            int4 dv = *(const int4*)(ei + E + e);
            int4 sv = *(const int4*)(ei + e);
            int ds[4] = {dv.x, dv.y, dv.z, dv.w};
            int ss[4] = {sv.x, sv.y, sv.z, sv.w};
#pragma unroll
            for (int j = 0; j < 4; ++j) {
                int p = atomicAdd(&cursor[(size_t)ds[j] * CPAD], 1);
                if (p < CAP) csr[((size_t)ds[j] << 6) + p] = ss[j];
            }
        }
        // scalar tail (E % 4) handled by block 0
        if (blockIdx.x == 0) {
            for (int e = E4 + tid; e < E; e += 256) {
                int d = ei[E + e], s = ei[e];
                int p = atomicAdd(&cursor[(size_t)d * CPAD], 1);
                if (p < CAP) csr[((size_t)d << 6) + p] = s;
            }
        }
        // self loops
        int stride = NFILL * 256;
        for (int n = blockIdx.x * 256 + tid; n < N; n += stride) {
            int p = atomicAdd(&cursor[(size_t)n * CPAD], 1);
            if (p < CAP) csr[((size_t)n << 6) + p] = n;
        }
        return;
    }

    const int node0 = (blockIdx.x - NFILL) * GN;

    // stage W transposed -> fp16, zero-padded k in [IN_F, 96)
    if (tid < 240) {
        int c = tid - (tid >= 160 ? 160 : (tid >= 80 ? 80 : 0));
        int kb = (tid >= 160 ? 64 : (tid >= 80 ? 32 : 0));
        h16 tmp[32];
#pragma unroll
        for (int j = 0; j < 32; ++j) {
            int k = kb + j;
            tmp[j] = (h16)((k < IN_F) ? W[k * F1 + c] : 0.f);
        }
        h16* dst = sWt + c * KS + kb;
#pragma unroll
        for (int j = 0; j < 4; ++j)
            *(h16x8*)(dst + j * 8) = *(const h16x8*)(tmp + j * 8);
    }
    __syncthreads();

    const int lane = tid & 63;
    const int m    = lane & 15;
    const int quad = lane >> 4;
    const int wn0  = (tid >> 6) * 16;

    int gn  = node0 + wn0 + m;
    int gnc = gn < N ? gn : N - 1;             // clamp: garbage rows discarded later
    const float* xr = x + (size_t)gnc * IN_F;

    f32x4 acc[5];
#pragma unroll
    for (int ct = 0; ct < 5; ++ct) acc[ct] = (f32x4){0.f, 0.f, 0.f, 0.f};

    // ks = 0, 32: A fully in-range (k <= 63 < 67)
#pragma unroll
    for (int ks = 0; ks < 64; ks += 32) {
        int k0 = ks + quad * 8;
        f32x4 a0 = *(const f32x4u*)(xr + k0);
        f32x4 a1 = *(const f32x4u*)(xr + k0 + 4);
        h16x8 af;
        af[0] = (h16)a0.x; af[1] = (h16)a0.y; af[2] = (h16)a0.z; af[3] = (h16)a0.w;
        af[4] = (h16)a1.x; af[5] = (h16)a1.y; af[6] = (h16)a1.z; af[7] = (h16)a1.w;
#pragma unroll
        for (int ct = 0; ct < 5; ++ct) {
            h16x8 bf = *(const h16x8*)(sWt + (ct * 16 + m) * KS + ks + quad * 8);
            acc[ct] = __builtin_amdgcn_mfma_f32_16x16x32_f16(af, bf, acc[ct], 0, 0, 0);
        }
    }
    // ks = 64: only quad 0 has valid k (64..66); rest zero (B pad is zero too)
    {
        h16x8 af = (h16x8)(h16)0.f;
        if (quad == 0) {
            af[0] = (h16)xr[64]; af[1] = (h16)xr[65]; af[2] = (h16)xr[66];
        }
#pragma unroll
        for (int ct = 0; ct < 5; ++ct) {
            h16x8 bf = *(const h16x8*)(sWt + (ct * 16 + m) * KS + 64 + quad * 8);
            acc[ct] = __builtin_amdgcn_mfma_f32_16x16x32_f16(af, bf, acc[ct], 0, 0, 0);
        }
    }
    __syncthreads();   // sWt reads done; repurpose smem as sO

    // C/D layout: col = lane&15, row = quad*4 + reg
#pragma unroll
    for (int ct = 0; ct < 5; ++ct)
#pragma unroll
        for (int r = 0; r < 4; ++r)
            sO[(wn0 + quad * 4 + r) * 81 + ct * 16 + m] = acc[ct][r];
    __syncthreads();

    // packed channel write-out: 40 h16x2 pairs per node, half-row layout
    for (int idx = tid; idx < GN * 40; idx += 256) {
        int n = idx / 40;
        int j = idx - n * 40;          // pair index 0..39
        int g8 = j / 20;               // head group
        int r  = j - g8 * 20;
        int hh = r >> 2;               // head within group 0..4
        int p  = r & 3;                // ch pair 0..3
        int gg = node0 + n;
        if (gg < N) {
            int h = g8 * 5 + hh;
            h16x2 v;
            v.x = (h16)sO[n * 81 + h * 8 + p * 2];
            v.y = (h16)sO[n * 81 + h * 8 + p * 2 + 1];
            *(h16x2*)(pk + (size_t)gg * PKS + g8 * 48 + hh * 8 + p * 2) = v;
        }
    }
    // attention logits: a_src fp16 at half-row offset 40..44; a_dst fp32
    for (int t = tid; t < GN * NH1; t += 256) {
        int n = t / NH1;
        int h = t - n * NH1;
        int gg = node0 + n;
        if (gg < N) {
            const float* hr = sO + n * 81 + h * NC1;
            float s = 0.f, d = 0.f;
#pragma unroll
            for (int c = 0; c < NC1; ++c) {
                float v = hr[c];
                s += v * att_s[h * NC1 + c];
                d += v * att_d[h * NC1 + c];
            }
            int g8 = h / 5, hh = h - g8 * 5;
            pk[(size_t)gg * PKS + g8 * 48 + 40 + hh] = (h16)s;
            a_dst[gg * NH1 + h] = d;
        }
    }
}

// ---------------- layer 1 aggregation FUSED with ELU + layer-2 projection --
// 2 threads per node, 5 heads each; per edge each thread reads 6 contiguous
// 16B chunks (96 B half-row) -> 12 gather requests/edge total (was 20).
__global__ __launch_bounds__(256)
void k_agg1(const int* __restrict__ cursor, const int* __restrict__ csr,
            const h16* __restrict__ pk, const float* __restrict__ a_dst,
            const float* __restrict__ b1, const float* __restrict__ W2,
            const float* __restrict__ att_s2, const float* __restrict__ att_d2,
            float2* __restrict__ hs2, float* __restrict__ a_dst2, int N) {
    __shared__ float spart[256];
    const int tid = threadIdx.x;
    const int n = blockIdx.x * 128 + (tid >> 1);
    const int g = tid & 1;

    float partial = 0.f;
    if (n < N) {
        int beg = n << 6;
        int cnt = cursor[(size_t)n * CPAD];
        cnt = cnt < CAP ? cnt : CAP;
        int end = beg + cnt;
        float ad[5];
#pragma unroll
        for (int hh = 0; hh < 5; ++hh) ad[hh] = a_dst[n * NH1 + g * 5 + hh];
        float den[5];
        float num[5][8];
#pragma unroll
        for (int hh = 0; hh < 5; ++hh) {
            den[hh] = 0.f;
#pragma unroll
            for (int c = 0; c < 8; ++c) num[hh][c] = 0.f;
        }
        const h16* pg = pk + g * 48;

        int i = beg;
        for (; i + 1 < end; i += 2) {
            int s0 = csr[i], s1 = csr[i + 1];
            const h16* r0 = pg + (size_t)s0 * PKS;
            const h16* r1 = pg + (size_t)s1 * PKS;
            h16x8 q0[5], q1[5];
#pragma unroll
            for (int hh = 0; hh < 5; ++hh) {
                q0[hh] = *(const h16x8*)(r0 + hh * 8);
                q1[hh] = *(const h16x8*)(r1 + hh * 8);
            }
            h16x8 as0 = *(const h16x8*)(r0 + 40);
            h16x8 as1 = *(const h16x8*)(r1 + 40);
#pragma unroll
            for (int hh = 0; hh < 5; ++hh) {
                float v0 = (float)as0[hh] + ad[hh];
                float v1 = (float)as1[hh] + ad[hh];
                v0 = v0 > 0.f ? v0 : 0.2f * v0;
                v1 = v1 > 0.f ? v1 : 0.2f * v1;
                float w0 = __expf(v0), w1 = __expf(v1);
                den[hh] += w0 + w1;
#pragma unroll
                for (int c = 0; c < 8; ++c)
                    num[hh][c] += w0 * (float)q0[hh][c] + w1 * (float)q1[hh][c];
            }
        }
        for (; i < end; ++i) {
            const h16* r0 = pg + (size_t)csr[i] * PKS;
            h16x8 q0[5];
#pragma unroll
            for (int hh = 0; hh < 5; ++hh) q0[hh] = *(const h16x8*)(r0 + hh * 8);
            h16x8 as0 = *(const h16x8*)(r0 + 40);
#pragma unroll
            for (int hh = 0; hh < 5; ++hh) {
                float v0 = (float)as0[hh] + ad[hh];
                v0 = v0 > 0.f ? v0 : 0.2f * v0;
                float w0 = __expf(v0);
                den[hh] += w0;
#pragma unroll
                for (int c = 0; c < 8; ++c) num[hh][c] += w0 * (float)q0[hh][c];
            }
        }
        // bias + elu + W2 dot (5 heads of this thread's group)
        float p = 0.f;
#pragma unroll
        for (int hh = 0; hh < 5; ++hh) {
            int h = g * 5 + hh;
            float inv = 1.f / den[hh];            // deg >= 1 (self-loop)
#pragma unroll
            for (int c = 0; c < 8; ++c) {
                float o = num[hh][c] * inv + b1[h * 8 + c];
                o = o > 0.f ? o : expm1f(o);      // elu
                p += o * W2[h * 8 + c];
            }
        }
        partial = p;
    }
    spart[tid] = partial;
    __syncthreads();
    if (tid < 128) {
        int nn = blockIdx.x * 128 + tid;
        if (nn < N) {
            float acc = spart[tid * 2] + spart[tid * 2 + 1];
            float2 v;
            v.x = acc;                  // hl2
            v.y = acc * att_s2[0];      // a_src2
            hs2[nn] = v;
            a_dst2[nn] = acc * att_d2[0];
        }
    }
}

// ---------------- layer 2 aggregation: one thread per node ----------------
__global__ __launch_bounds__(256)
void k_agg2(const int* __restrict__ cursor, const int* __restrict__ csr,
            const float2* __restrict__ hs2, const float* __restrict__ a_dst2,
            const float* __restrict__ b2, float* __restrict__ out, int N) {
    int n = blockIdx.x * blockDim.x + threadIdx.x;
    if (n >= N) return;
    float ad = a_dst2[n];
    float den = 0.f, num = 0.f;
    int beg = n << 6;
    int cnt = cursor[(size_t)n * CPAD];
    cnt = cnt < CAP ? cnt : CAP;
    int end = beg + cnt;
    int i = beg;
    for (; i + 7 < end; i += 8) {
        int sv[8];
#pragma unroll
        for (int j = 0; j < 8; ++j) sv[j] = csr[i + j];
        float2 g[8];
#pragma unroll
        for (int j = 0; j < 8; ++j) g[j] = hs2[sv[j]];
#pragma unroll
        for (int j = 0; j < 8; ++j) {
            float v = g[j].y + ad;
            v = v > 0.f ? v : 0.2f * v;
            float w = __expf(v);
            den += w;
            num += w * g[j].x;
        }
    }
    for (; i < end; ++i) {
        float2 g = hs2[csr[i]];
        float v = g.y + ad;
        v = v > 0.f ? v : 0.2f * v;
        float w = __expf(v);
        den += w;
        num += w * g.x;
    }
    out[n] = num / den + b2[0];
}

extern "C" void kernel_launch(void* const* d_in, const int* in_sizes, int n_in,
                              void* d_out, int out_size, void* d_ws, size_t ws_size,
                              hipStream_t stream) {
    const float* x        = (const float*)d_in[0];
    const int*   ei       = (const int*)d_in[1];
    const float* W1       = (const float*)d_in[2];
    const float* att_src1 = (const float*)d_in[3];
    const float* att_dst1 = (const float*)d_in[4];
    const float* b1       = (const float*)d_in[5];
    const float* W2       = (const float*)d_in[6];
    const float* att_src2 = (const float*)d_in[7];
    const float* att_dst2 = (const float*)d_in[8];
    const float* b2       = (const float*)d_in[9];
    float* out = (float*)d_out;

    const int N  = in_sizes[0] / IN_F;   // 100000
    const int E  = in_sizes[1] / 2;      // 1600000
    const int EN = E + N;                // with self-loops

    // workspace layout (4-byte slots)
    float*  ws      = (float*)d_ws;
    h16*    pk      = (h16*)ws;                        // N*PKS h16
    float*  a_dst1  = ws + (size_t)N * (PKS / 2);      // N*NH1
    float2* hs2     = (float2*)(a_dst1 + (size_t)N * NH1);  // N float2
    float*  a_dst2  = (float*)(hs2 + N);               // N
    int*    cursor  = (int*)(a_dst2 + N);              // N*CPAD (padded counters)
    int*    csr     = cursor + (size_t)N * CPAD;       // N*CAP bucket slots

    const int B = 256;
    const int nbG = (N + GN - 1) / GN;                 // 1563

    // ---- zero padded counters, then fused bucket build + GEMM ----
    hipMemsetAsync(cursor, 0, (size_t)N * CPAD * sizeof(int), stream);
    k_front<<<NFILL + nbG, 256, 0, stream>>>(x, W1, att_src1, att_dst1, ei,
                                             cursor, csr, pk, a_dst1, N, E, EN);

    // ---- layer 1 aggregation (+ fused ELU + layer-2 projection) ----
    k_agg1 <<<(N + 127) / 128, 256, 0, stream>>>(cursor, csr, pk, a_dst1,
                                                 b1, W2, att_src2, att_dst2,
                                                 hs2, a_dst2, N);

    // ---- layer 2 ----
    k_agg2 <<<(N + B - 1) / B, B, 0, stream>>>(cursor, csr, hs2, a_dst2, b2, out, N);
}

// Round 11
// 280.953 us; speedup vs baseline: 1.2130x; 1.2130x over previous
//
#include <hip/hip_runtime.h>
#include <math.h>

#define IN_F 67
#define F1   80   // H1*C1
#define NH1  10
#define NC1  8

#define GN   64           // nodes per GEMM block
#define KS   104          // sWt row stride in h16 (208 B, 16B-aligned frags)
#define NPB  25           // nodes per agg1 block (25*10 = 250 active threads)
#define PKS  96           // packed row stride in h16 (192 B = 3 cache lines)
#define CAP  64           // bucket capacity per node (P(deg>63) ~ 1e-17)
#define CPAD 16           // cursor stride in ints (64 B: 1 atomic counter/line)
#define NCHUNK 128        // fill chunks per XCD group (128*8 = 1024 blocks)

typedef _Float16 h16;
typedef h16 h16x2 __attribute__((ext_vector_type(2)));
typedef h16 h16x8 __attribute__((ext_vector_type(8)));
typedef float f32x4 __attribute__((ext_vector_type(4)));
typedef float f32x4u __attribute__((ext_vector_type(4), aligned(4)));
typedef int i32x4 __attribute__((ext_vector_type(4)));

// ---------------- front: block-specialized GEMM | bucket CSR build --------
// blocks [0,nbG): lean MFMA GEMM + logits (A-frags straight from global x,
//   only W^T in LDS; pk row = 80 h fp16 + 10 a_src fp16 + pad). pk/a_dst
//   stores are non-temporal (consumed next kernel, keep L2 for fill buckets).
// blocks [nbG, nbG+NCHUNK*8): bucket fill. XCD group g = blockIdx&7 owns dst
//   range g*(N/8) so each group's csr slice (3.2 MB) is L2-resident; ei is
//   streamed with non-temporal loads to avoid evicting the buckets.
__global__ __launch_bounds__(256)
void k_front(const float* __restrict__ x, const float* __restrict__ W,
             const float* __restrict__ att_s, const float* __restrict__ att_d,
             const int* __restrict__ ei, int* __restrict__ cursor,
             int* __restrict__ csr, h16* __restrict__ pk,
             float* __restrict__ a_dst, int N, int E, int EN, int nbG) {
    __shared__ __align__(16) char smem[GN * 81 * 4];   // 20736 B
    h16*   sWt = (h16*)smem;                           // 80*KS*2 = 16640 B
    float* sO  = (float*)smem;                         // aliased after barrier

    const int tid = threadIdx.x;

    if ((int)blockIdx.x >= nbG) {
        // ---- bucket-fill blocks ----
        int xcd   = blockIdx.x & 7;          // physical-XCD locality heuristic
        int chunk = (blockIdx.x - nbG) >> 3; // 0 .. NCHUNK-1
        int range = (N + 7) >> 3;
        int lo = xcd * range, hi = lo + range;

        // real edges, int4-vectorized non-temporal stream
        const int E4 = E & ~3;
        int stride4 = NCHUNK * 256 * 4;
        for (int e = (chunk * 256 + tid) * 4; e < E4; e += stride4) {
            i32x4 dv = __builtin_nontemporal_load((const i32x4*)(ei + E + e));
            i32x4 sv = __builtin_nontemporal_load((const i32x4*)(ei + e));
#pragma unroll
            for (int j = 0; j < 4; ++j) {
                int d = dv[j];
                if (d >= lo && d < hi) {
                    int p = atomicAdd(&cursor[(size_t)d * CPAD], 1);
                    if (p < CAP) csr[((size_t)d << 6) + p] = sv[j];
                }
            }
        }
        // scalar tail
        for (int e = E4 + chunk * 256 + tid; e < E; e += NCHUNK * 256) {
            int d = ei[E + e];
            if (d >= lo && d < hi) {
                int p = atomicAdd(&cursor[(size_t)d * CPAD], 1);
                if (p < CAP) csr[((size_t)d << 6) + p] = ei[e];
            }
        }
        // self loops (always in this group's range)
        for (int n = lo + chunk * 256 + tid; n < hi && n < N; n += NCHUNK * 256) {
            int p = atomicAdd(&cursor[(size_t)n * CPAD], 1);
            if (p < CAP) csr[((size_t)n << 6) + p] = n;
        }
        return;
    }

    const int node0 = blockIdx.x * GN;

    // stage W transposed -> fp16, zero-padded k in [IN_F, 96)
    if (tid < 240) {
        int c = tid - (tid >= 160 ? 160 : (tid >= 80 ? 80 : 0));
        int kb = (tid >= 160 ? 64 : (tid >= 80 ? 32 : 0));
        h16 tmp[32];
#pragma unroll
        for (int j = 0; j < 32; ++j) {
            int k = kb + j;
            tmp[j] = (h16)((k < IN_F) ? W[k * F1 + c] : 0.f);
        }
        h16* dst = sWt + c * KS + kb;
#pragma unroll
        for (int j = 0; j < 4; ++j)
            *(h16x8*)(dst + j * 8) = *(const h16x8*)(tmp + j * 8);
    }
    __syncthreads();

    const int lane = tid & 63;
    const int m    = lane & 15;
    const int quad = lane >> 4;
    const int wn0  = (tid >> 6) * 16;

    int gn  = node0 + wn0 + m;
    int gnc = gn < N ? gn : N - 1;             // clamp: garbage rows discarded later
    const float* xr = x + (size_t)gnc * IN_F;

    f32x4 acc[5];
#pragma unroll
    for (int ct = 0; ct < 5; ++ct) acc[ct] = (f32x4){0.f, 0.f, 0.f, 0.f};

    // ks = 0, 32: A fully in-range (k <= 63 < 67)
#pragma unroll
    for (int ks = 0; ks < 64; ks += 32) {
        int k0 = ks + quad * 8;
        f32x4 a0 = *(const f32x4u*)(xr + k0);
        f32x4 a1 = *(const f32x4u*)(xr + k0 + 4);
        h16x8 af;
        af[0] = (h16)a0.x; af[1] = (h16)a0.y; af[2] = (h16)a0.z; af[3] = (h16)a0.w;
        af[4] = (h16)a1.x; af[5] = (h16)a1.y; af[6] = (h16)a1.z; af[7] = (h16)a1.w;
#pragma unroll
        for (int ct = 0; ct < 5; ++ct) {
            h16x8 bf = *(const h16x8*)(sWt + (ct * 16 + m) * KS + ks + quad * 8);
            acc[ct] = __builtin_amdgcn_mfma_f32_16x16x32_f16(af, bf, acc[ct], 0, 0, 0);
        }
    }
    // ks = 64: only quad 0 has valid k (64..66); rest zero (B pad is zero too)
    {
        h16x8 af = (h16x8)(h16)0.f;
        if (quad == 0) {
            af[0] = (h16)xr[64]; af[1] = (h16)xr[65]; af[2] = (h16)xr[66];
        }
#pragma unroll
        for (int ct = 0; ct < 5; ++ct) {
            h16x8 bf = *(const h16x8*)(sWt + (ct * 16 + m) * KS + 64 + quad * 8);
            acc[ct] = __builtin_amdgcn_mfma_f32_16x16x32_f16(af, bf, acc[ct], 0, 0, 0);
        }
    }
    __syncthreads();   // sWt reads done; repurpose smem as sO

    // C/D layout: col = lane&15, row = quad*4 + reg
#pragma unroll
    for (int ct = 0; ct < 5; ++ct)
#pragma unroll
        for (int r = 0; r < 4; ++r)
            sO[(wn0 + quad * 4 + r) * 81 + ct * 16 + m] = acc[ct][r];
    __syncthreads();

    // packed h write-out as fp16 pairs (non-temporal: consumed next kernel)
    for (int idx = tid; idx < GN * (F1 / 2); idx += 256) {
        int n = idx / (F1 / 2);
        int p = idx - n * (F1 / 2);
        int g = node0 + n;
        if (g < N) {
            h16x2 v;
            v.x = (h16)sO[n * 81 + 2 * p];
            v.y = (h16)sO[n * 81 + 2 * p + 1];
            __builtin_nontemporal_store(*(int*)&v, (int*)(pk + (size_t)g * PKS + 2 * p));
        }
    }
    // attention logits: a_src packed fp16 into row; a_dst fp32 separate
    for (int t = tid; t < GN * NH1; t += 256) {
        int n = t / NH1;
        int h = t - n * NH1;
        int g = node0 + n;
        if (g < N) {
            const float* hr = sO + n * 81 + h * NC1;
            float s = 0.f, d = 0.f;
#pragma unroll
            for (int c = 0; c < NC1; ++c) {
                float v = hr[c];
                s += v * att_s[h * NC1 + c];
                d += v * att_d[h * NC1 + c];
            }
            h16 sh = (h16)s;
            __builtin_nontemporal_store(*(short*)&sh, (short*)(pk + (size_t)g * PKS + F1 + h));
            __builtin_nontemporal_store(d, a_dst + g * NH1 + h);
        }
    }
}

// ---------------- layer 1 aggregation FUSED with ELU + layer-2 projection --
__global__ __launch_bounds__(256)
void k_agg1(const int* __restrict__ cursor, const int* __restrict__ csr,
            const h16* __restrict__ pk, const float* __restrict__ a_dst,
            const float* __restrict__ b1, const float* __restrict__ W2,
            const float* __restrict__ att_s2, const float* __restrict__ att_d2,
            float2* __restrict__ hs2, float* __restrict__ a_dst2, int N) {
    __shared__ float spart[256];
    const int tid = threadIdx.x;
    const int node0 = blockIdx.x * NPB;

    float partial = 0.f;
    if (tid < NPB * NH1) {
        int n_l = tid / NH1;
        int h = tid - n_l * NH1;
        int n = node0 + n_l;
        if (n < N) {
            int beg = n << 6;
            int cnt = cursor[(size_t)n * CPAD];
            cnt = cnt < CAP ? cnt : CAP;
            int end = beg + cnt;
            float ad = a_dst[n * NH1 + h];
            float den = 0.f;
            float num[NC1];
#pragma unroll
            for (int c = 0; c < NC1; ++c) num[c] = 0.f;

            int i = beg;
            for (; i + 7 < end; i += 8) {
                int sv[8];
#pragma unroll
                for (int j = 0; j < 8; ++j) sv[j] = csr[i + j];
                h16x8 q[8];
                float a[8];
#pragma unroll
                for (int j = 0; j < 8; ++j) {
                    const h16* rp = pk + (size_t)sv[j] * PKS;
                    q[j] = *(const h16x8*)(rp + h * NC1);
                    a[j] = (float)rp[F1 + h];
                }
#pragma unroll
                for (int j = 0; j < 8; ++j) {
                    float v = a[j] + ad;
                    v = v > 0.f ? v : 0.2f * v;
                    float w = __expf(v);
                    den += w;
#pragma unroll
                    for (int c = 0; c < NC1; ++c) num[c] += w * (float)q[j][c];
                }
            }
            for (; i + 3 < end; i += 4) {
                int sv[4];
#pragma unroll
                for (int j = 0; j < 4; ++j) sv[j] = csr[i + j];
                h16x8 q[4];
                float a[4];
#pragma unroll
                for (int j = 0; j < 4; ++j) {
                    const h16* rp = pk + (size_t)sv[j] * PKS;
                    q[j] = *(const h16x8*)(rp + h * NC1);
                    a[j] = (float)rp[F1 + h];
                }
#pragma unroll
                for (int j = 0; j < 4; ++j) {
                    float v = a[j] + ad;
                    v = v > 0.f ? v : 0.2f * v;
                    float w = __expf(v);
                    den += w;
#pragma unroll
                    for (int c = 0; c < NC1; ++c) num[c] += w * (float)q[j][c];
                }
            }
            for (; i < end; ++i) {
                const h16* rp = pk + (size_t)csr[i] * PKS;
                h16x8 q = *(const h16x8*)(rp + h * NC1);
                float v = (float)rp[F1 + h] + ad;
                v = v > 0.f ? v : 0.2f * v;
                float w = __expf(v);
                den += w;
#pragma unroll
                for (int c = 0; c < NC1; ++c) num[c] += w * (float)q[c];
            }
            float inv = 1.f / den;                 // deg >= 1 (self-loop)
            const float* bb = b1 + h * NC1;
            const float* w2 = W2 + h * NC1;
            float p = 0.f;
#pragma unroll
            for (int c = 0; c < NC1; ++c) {
                float o = num[c] * inv + bb[c];
                o = o > 0.f ? o : expm1f(o);       // elu
                p += o * w2[c];
            }
            partial = p;
        }
    }
    spart[tid] = partial;
    __syncthreads();
    if (tid < NPB) {
        int n = node0 + tid;
        if (n < N) {
            float acc = 0.f;
#pragma unroll
            for (int h = 0; h < NH1; ++h) acc += spart[tid * NH1 + h];
            float2 v;
            v.x = acc;                  // hl2
            v.y = acc * att_s2[0];      // a_src2
            hs2[n] = v;
            a_dst2[n] = acc * att_d2[0];
        }
    }
}

// ---------------- layer 2 aggregation: one thread per node ----------------
__global__ __launch_bounds__(256)
void k_agg2(const int* __restrict__ cursor, const int* __restrict__ csr,
            const float2* __restrict__ hs2, const float* __restrict__ a_dst2,
            const float* __restrict__ b2, float* __restrict__ out, int N) {
    int n = blockIdx.x * blockDim.x + threadIdx.x;
    if (n >= N) return;
    float ad = a_dst2[n];
    float den = 0.f, num = 0.f;
    int beg = n << 6;
    int cnt = cursor[(size_t)n * CPAD];
    cnt = cnt < CAP ? cnt : CAP;
    int end = beg + cnt;
    int i = beg;
    for (; i + 7 < end; i += 8) {
        int sv[8];
#pragma unroll
        for (int j = 0; j < 8; ++j) sv[j] = csr[i + j];
        float2 g[8];
#pragma unroll
        for (int j = 0; j < 8; ++j) g[j] = hs2[sv[j]];
#pragma unroll
        for (int j = 0; j < 8; ++j) {
            float v = g[j].y + ad;
            v = v > 0.f ? v : 0.2f * v;
            float w = __expf(v);
            den += w;
            num += w * g[j].x;
        }
    }
    for (; i < end; ++i) {
        float2 g = hs2[csr[i]];
        float v = g.y + ad;
        v = v > 0.f ? v : 0.2f * v;
        float w = __expf(v);
        den += w;
        num += w * g.x;
    }
    out[n] = num / den + b2[0];
}

extern "C" void kernel_launch(void* const* d_in, const int* in_sizes, int n_in,
                              void* d_out, int out_size, void* d_ws, size_t ws_size,
                              hipStream_t stream) {
    const float* x        = (const float*)d_in[0];
    const int*   ei       = (const int*)d_in[1];
    const float* W1       = (const float*)d_in[2];
    const float* att_src1 = (const float*)d_in[3];
    const float* att_dst1 = (const float*)d_in[4];
    const float* b1       = (const float*)d_in[5];
    const float* W2       = (const float*)d_in[6];
    const float* att_src2 = (const float*)d_in[7];
    const float* att_dst2 = (const float*)d_in[8];
    const float* b2       = (const float*)d_in[9];
    float* out = (float*)d_out;

    const int N  = in_sizes[0] / IN_F;   // 100000
    const int E  = in_sizes[1] / 2;      // 1600000
    const int EN = E + N;                // with self-loops

    // workspace layout (4-byte slots)
    float*  ws      = (float*)d_ws;
    h16*    pk      = (h16*)ws;                        // N*PKS h16
    float*  a_dst1  = ws + (size_t)N * (PKS / 2);      // N*NH1
    float2* hs2     = (float2*)(a_dst1 + (size_t)N * NH1);  // N float2
    float*  a_dst2  = (float*)(hs2 + N);               // N
    int*    cursor  = (int*)(a_dst2 + N);              // N*CPAD (padded counters)
    int*    csr     = cursor + (size_t)N * CPAD;       // N*CAP bucket slots

    const int B = 256;
    const int nbG = (N + GN - 1) / GN;                 // 1563

    // ---- zero padded counters, then fused GEMM + bucket CSR build ----
    hipMemsetAsync(cursor, 0, (size_t)N * CPAD * sizeof(int), stream);
    k_front<<<nbG + NCHUNK * 8, 256, 0, stream>>>(x, W1, att_src1, att_dst1, ei,
                                                  cursor, csr, pk, a_dst1,
                                                  N, E, EN, nbG);

    // ---- layer 1 aggregation (+ fused ELU + layer-2 projection) ----
    k_agg1 <<<(N + NPB - 1) / NPB, 256, 0, stream>>>(cursor, csr, pk, a_dst1,
                                                     b1, W2, att_src2, att_dst2,
                                                     hs2, a_dst2, N);

    // ---- layer 2 ----
    k_agg2 <<<(N + B - 1) / B, B, 0, stream>>>(cursor, csr, hs2, a_dst2, b2, out, N);
}